// Round 3
// baseline (2163.115 us; speedup 1.0000x reference)
//
#include <hip/hip_runtime.h>

typedef unsigned short u16;
struct __align__(16) us8 { ushort4 a, b; };
typedef __attribute__((ext_vector_type(8))) short bf16x8;
typedef __attribute__((ext_vector_type(4))) float f32x4;

#define CDIV(a,b) (((a)+(b)-1)/(b))

__device__ __forceinline__ float bf2f(u16 u){ return __uint_as_float(((unsigned)u)<<16); }
__device__ __forceinline__ u16 f2bf(float f){
  unsigned u=__float_as_uint(f);
  unsigned r=u+0x7fffu+((u>>16)&1u);
  return (u16)(r>>16);
}
__device__ __forceinline__ float lrelu_f(float v){ return v>0.f? v:0.01f*v; }
__device__ __forceinline__ float wsum(float v){
  #pragma unroll
  for(int o=32;o>0;o>>=1) v+=__shfl_xor(v,o,64);
  return v;
}
__device__ __forceinline__ void us8_to_f(const us8& v, float* f){
  f[0]=bf2f(v.a.x); f[1]=bf2f(v.a.y); f[2]=bf2f(v.a.z); f[3]=bf2f(v.a.w);
  f[4]=bf2f(v.b.x); f[5]=bf2f(v.b.y); f[6]=bf2f(v.b.z); f[7]=bf2f(v.b.w);
}
__device__ __forceinline__ us8 f_to_us8(const float* f){
  us8 v;
  v.a.x=f2bf(f[0]); v.a.y=f2bf(f[1]); v.a.z=f2bf(f[2]); v.a.w=f2bf(f[3]);
  v.b.x=f2bf(f[4]); v.b.y=f2bf(f[5]); v.b.z=f2bf(f[6]); v.b.w=f2bf(f[7]);
  return v;
}

// ---------------- utility ----------------
__global__ void zero_k(unsigned* __restrict__ p, int n){
  int i=blockIdx.x*256+threadIdx.x; if(i<n) p[i]=0u;
}
__global__ void cvt_k(const float* __restrict__ in, u16* __restrict__ out, int n){
  int i = (blockIdx.x*256+threadIdx.x)*4;
  if(i+3<n){
    float4 v=*(const float4*)(in+i);
    ushort4 o; o.x=f2bf(v.x); o.y=f2bf(v.y); o.z=f2bf(v.z); o.w=f2bf(v.w);
    *(ushort4*)(out+i)=o;
  } else {
    for(int q=0;q<4&&i+q<n;q++) out[i+q]=f2bf(in[i+q]);
  }
}

// ---------------- CSR build ----------------
__global__ void count_k(const int* __restrict__ src, const int* __restrict__ dst, int E,
                        int* __restrict__ cnt_src, int* __restrict__ cnt_dst){
  int e = blockIdx.x*256+threadIdx.x;
  if(e>=E) return;
  atomicAdd(&cnt_src[src[e]],1);
  atomicAdd(&cnt_dst[dst[e]],1);
}

#define SCAN_CHUNK 1024
__global__ void scan_pass1(const int* __restrict__ in, int n, int* __restrict__ partial){
  __shared__ int red[256];
  int base = blockIdx.x*SCAN_CHUNK;
  int s=0;
  for(int j=threadIdx.x;j<SCAN_CHUNK;j+=256){ int i=base+j; if(i<n) s+=in[i]; }
  red[threadIdx.x]=s; __syncthreads();
  for(int st=128;st>0;st>>=1){ if(threadIdx.x<st) red[threadIdx.x]+=red[threadIdx.x+st]; __syncthreads(); }
  if(threadIdx.x==0) partial[blockIdx.x]=red[0];
}
__global__ void scan_pass2(int* __restrict__ partial, int nb){
  __shared__ int buf[1024];
  for(int j=threadIdx.x;j<1024;j+=256) buf[j] = (j<nb)? partial[j]:0;
  __syncthreads();
  if(threadIdx.x==0){ int run=0; for(int j=0;j<nb;j++){ int v=buf[j]; buf[j]=run; run+=v; } }
  __syncthreads();
  for(int j=threadIdx.x;j<nb;j+=256) partial[j]=buf[j];
}
__global__ void scan_pass3(const int* __restrict__ in, int n, const int* __restrict__ partial,
                           int* __restrict__ out, int total){
  __shared__ int red[256];
  int base = blockIdx.x*SCAN_CHUNK;
  int j0 = base + threadIdx.x*4;
  int v[4]; int s=0;
  #pragma unroll
  for(int q=0;q<4;q++){ int i=j0+q; v[q]=(i<n)? in[i]:0; s+=v[q]; }
  red[threadIdx.x]=s; __syncthreads();
  if(threadIdx.x==0){ int run=0; for(int j=0;j<256;j++){ int t=red[j]; red[j]=run; run+=t; } }
  __syncthreads();
  int run = partial[blockIdx.x] + red[threadIdx.x];
  #pragma unroll
  for(int q=0;q<4;q++){ int i=j0+q; if(i<n) out[i]=run; run+=v[q]; }
  if(base==0 && threadIdx.x==0) out[n]=total;
}
__global__ void copy_int_k(const int* __restrict__ in, int* __restrict__ out, int n){
  int i=blockIdx.x*256+threadIdx.x;
  if(i<n) out[i]=in[i];
}
__global__ void fill_adj_k(const int* __restrict__ src, const int* __restrict__ dst, int E,
                           int* __restrict__ cur_src, int* __restrict__ cur_dst,
                           int* __restrict__ adj_sd, int* __restrict__ adj_ds){
  int e = blockIdx.x*256+threadIdx.x;
  if(e>=E) return;
  int s=src[e], d=dst[e];
  int p = atomicAdd(&cur_dst[d],1); adj_ds[p]=s;   // dst-grouped, values = src
  int q = atomicAdd(&cur_src[s],1); adj_sd[q]=d;   // src-grouped, values = dst
}
__global__ void invdeg_k(const int* __restrict__ off, float* __restrict__ inv, int S){
  int s=blockIdx.x*256+threadIdx.x;
  if(s>=S) return;
  int d=off[s+1]-off[s];
  inv[s] = d>0 ? 1.0f/(float)d : 0.0f;
}

// ---------------- row-wise ops (wave per row, H=256) ----------------
__global__ void l2norm_k(const float* __restrict__ in, u16* __restrict__ out, int R){
  int r = blockIdx.x*4 + (threadIdx.x>>6);
  if(r>=R) return;
  int c = (threadIdx.x&63)*4;
  float4 v = *(const float4*)(in + (size_t)r*256 + c);
  float q = wsum(v.x*v.x+v.y*v.y+v.z*v.z+v.w*v.w);
  float sc = 1.0f/fmaxf(sqrtf(q),1e-12f);
  ushort4 o; o.x=f2bf(v.x*sc); o.y=f2bf(v.y*sc); o.z=f2bf(v.z*sc); o.w=f2bf(v.w*sc);
  *(ushort4*)(out + (size_t)r*256 + c) = o;
}

__global__ void ln_rows_k(u16* __restrict__ x, const float* __restrict__ g,
                          const float* __restrict__ b, int R){
  int r = blockIdx.x*4 + (threadIdx.x>>6);
  if(r>=R) return;
  int lane = threadIdx.x&63; int c = lane*4;
  u16* row = x + (size_t)r*256;
  ushort4 u = *(const ushort4*)(row + c);
  float v0=bf2f(u.x), v1=bf2f(u.y), v2=bf2f(u.z), v3=bf2f(u.w);
  float mean = wsum(v0+v1+v2+v3) * (1.f/256.f);
  float d0=v0-mean,d1=v1-mean,d2=v2-mean,d3=v3-mean;
  float var = wsum(d0*d0+d1*d1+d2*d2+d3*d3) * (1.f/256.f);
  float inv = 1.0f/sqrtf(var + 1e-5f);
  ushort4 ov;
  ov.x=f2bf(d0*inv*g[c+0]+b[c+0]);
  ov.y=f2bf(d1*inv*g[c+1]+b[c+1]);
  ov.z=f2bf(d2*inv*g[c+2]+b[c+2]);
  ov.w=f2bf(d3*inv*g[c+3]+b[c+3]);
  *(ushort4*)(row + c) = ov;
}

// joint LayerNorm over virtual concat [L|R], width 512, in place
__global__ void ln512_k(u16* __restrict__ Lb, u16* __restrict__ Rb,
                        const float* __restrict__ g, const float* __restrict__ b, int R){
  int r = blockIdx.x*4 + (threadIdx.x>>6);
  if(r>=R) return;
  int lane = threadIdx.x&63; int c = lane*4;
  u16* rowL = Lb + (size_t)r*256;
  u16* rowR = Rb + (size_t)r*256;
  ushort4 ul = *(const ushort4*)(rowL + c);
  ushort4 ur = *(const ushort4*)(rowR + c);
  float l0=bf2f(ul.x), l1=bf2f(ul.y), l2=bf2f(ul.z), l3=bf2f(ul.w);
  float r0=bf2f(ur.x), r1=bf2f(ur.y), r2=bf2f(ur.z), r3=bf2f(ur.w);
  float mean = wsum(l0+l1+l2+l3+r0+r1+r2+r3) * (1.f/512.f);
  float a0=l0-mean,a1=l1-mean,a2=l2-mean,a3=l3-mean;
  float b0=r0-mean,b1=r1-mean,b2=r2-mean,b3=r3-mean;
  float var = wsum(a0*a0+a1*a1+a2*a2+a3*a3+b0*b0+b1*b1+b2*b2+b3*b3) * (1.f/512.f);
  float inv = 1.0f/sqrtf(var + 1e-5f);
  int cr = 256+c;
  ushort4 ovl, ovr;
  ovl.x=f2bf(a0*inv*g[c+0]+b[c+0]);
  ovl.y=f2bf(a1*inv*g[c+1]+b[c+1]);
  ovl.z=f2bf(a2*inv*g[c+2]+b[c+2]);
  ovl.w=f2bf(a3*inv*g[c+3]+b[c+3]);
  ovr.x=f2bf(b0*inv*g[cr+0]+b[cr+0]);
  ovr.y=f2bf(b1*inv*g[cr+1]+b[cr+1]);
  ovr.z=f2bf(b2*inv*g[cr+2]+b[cr+2]);
  ovr.w=f2bf(b3*inv*g[cr+3]+b[cr+3]);
  *(ushort4*)(rowL + c) = ovl;
  *(ushort4*)(rowR + c) = ovr;
}

// ---------------- GraphNorm ----------------
__global__ void colstat_k(const u16* __restrict__ x, const u16* __restrict__ x2,
                          float* __restrict__ stat, int R){
  __shared__ float sh[512];
  int tid = threadIdx.x;
  for(int j=tid;j<512;j+=256) sh[j]=0.f;
  __syncthreads();
  int c = (tid&63)*4;
  float s0=0,s1=0,s2=0,s3=0,q0=0,q1=0,q2=0,q3=0;
  for(int r=blockIdx.x*4+(tid>>6); r<R; r+=gridDim.x*4){
    ushort4 u = *(const ushort4*)(x + (size_t)r*256 + c);
    float v0=bf2f(u.x), v1=bf2f(u.y), v2=bf2f(u.z), v3=bf2f(u.w);
    if(x2){
      ushort4 w = *(const ushort4*)(x2 + (size_t)r*256 + c);
      v0+=bf2f(w.x); v1+=bf2f(w.y); v2+=bf2f(w.z); v3+=bf2f(w.w);
    }
    s0+=v0; s1+=v1; s2+=v2; s3+=v3;
    q0+=v0*v0; q1+=v1*v1; q2+=v2*v2; q3+=v3*v3;
  }
  atomicAdd(&sh[c+0],s0); atomicAdd(&sh[c+1],s1);
  atomicAdd(&sh[c+2],s2); atomicAdd(&sh[c+3],s3);
  atomicAdd(&sh[256+c+0],q0); atomicAdd(&sh[256+c+1],q1);
  atomicAdd(&sh[256+c+2],q2); atomicAdd(&sh[256+c+3],q3);
  __syncthreads();
  for(int j=tid;j<512;j+=256) atomicAdd(&stat[j], sh[j]);
}
__global__ void gn_final_k(const float* __restrict__ stat, const float* __restrict__ w,
                           const float* __restrict__ b, const float* __restrict__ ms,
                           float eps, float invR,
                           float* __restrict__ gA, float* __restrict__ gS, float* __restrict__ gB){
  int c=threadIdx.x;
  float mean = stat[c]*invR;
  float a = mean*ms[c];
  float ex2 = stat[256+c]*invR;
  float var = ex2 - 2.f*a*mean + a*a;     // E[(x-a)^2]
  gA[c]=a;
  gS[c]=w[c]/sqrtf(var+eps);
  gB[c]=b[c];
}
__global__ void apply_gn_k(u16* __restrict__ x, const u16* __restrict__ add,
                           const float* __restrict__ gA, const float* __restrict__ gS,
                           const float* __restrict__ gB, size_t n4){
  size_t stride = (size_t)gridDim.x*256;
  for(size_t p=(size_t)blockIdx.x*256+threadIdx.x; p<n4; p+=stride){
    int c = (int)(p&63)*4;
    ushort4 u = ((const ushort4*)x)[p];
    float v0=bf2f(u.x), v1=bf2f(u.y), v2=bf2f(u.z), v3=bf2f(u.w);
    if(add){
      ushort4 a = ((const ushort4*)add)[p];
      v0+=bf2f(a.x); v1+=bf2f(a.y); v2+=bf2f(a.z); v3+=bf2f(a.w);
    }
    v0 = fmaf(gS[c+0], v0-gA[c+0], gB[c+0]);
    v1 = fmaf(gS[c+1], v1-gA[c+1], gB[c+1]);
    v2 = fmaf(gS[c+2], v2-gA[c+2], gB[c+2]);
    v3 = fmaf(gS[c+3], v3-gA[c+3], gB[c+3]);
    ushort4 o; o.x=f2bf(v0); o.y=f2bf(v1); o.z=f2bf(v2); o.w=f2bf(v3);
    ((ushort4*)x)[p]=o;
  }
}

// ---------------- segment gathers (half-wave per segment, 8 cols/lane) ----------------
// MODE 0: out[s] = inv[s]*sum
// MODE 1: out[s] = lrelu(inv[s]*sum + bias) + gS*(resid[s]-gA)+gB
// MODE 2: out[s] = lrelu(inv[s]*sum + bias) + resid[s]
template<int MODE>
__global__ void seg_sum_k(const u16* __restrict__ in, u16* __restrict__ out,
    const int* __restrict__ adj, const int* __restrict__ off,
    const float* __restrict__ inv, const float* __restrict__ bias,
    const u16* __restrict__ resid,
    const float* __restrict__ gA, const float* __restrict__ gS, const float* __restrict__ gB,
    int S){
  int s = blockIdx.x*8 + (threadIdx.x>>5);
  if(s>=S) return;
  int c = (threadIdx.x&31)*8;
  int jb=off[s], je=off[s+1];
  float a[8]={0.f,0.f,0.f,0.f,0.f,0.f,0.f,0.f};
  for(int j=jb;j<je;j++){
    us8 v = *(const us8*)(in + (size_t)adj[j]*256 + c);
    float f[8]; us8_to_f(v,f);
    #pragma unroll
    for(int q=0;q<8;q++) a[q]+=f[q];
  }
  float sc = inv[s];
  float o[8];
  if(MODE==0){
    #pragma unroll
    for(int q=0;q<8;q++) o[q]=a[q]*sc;
  } else {
    #pragma unroll
    for(int q=0;q<8;q++) o[q] = lrelu_f(fmaf(a[q],sc,bias[c+q]));
    us8 p = *(const us8*)(resid + (size_t)s*256 + c);
    float pf[8]; us8_to_f(p,pf);
    if(MODE==1){
      #pragma unroll
      for(int q=0;q<8;q++) o[q] += fmaf(gS[c+q], pf[q]-gA[c+q], gB[c+q]);
    } else {
      #pragma unroll
      for(int q=0;q<8;q++) o[q] += pf[q];
    }
  }
  *(us8*)(out + (size_t)s*256 + c) = f_to_us8(o);
}

__global__ void seg_min_k(const u16* __restrict__ in, u16* __restrict__ out,
    const int* __restrict__ adj, const int* __restrict__ off, int S){
  int s = blockIdx.x*8 + (threadIdx.x>>5);
  if(s>=S) return;
  int c = (threadIdx.x&31)*8;
  int jb=off[s], je=off[s+1];
  float m[8];
  #pragma unroll
  for(int q=0;q<8;q++) m[q]=3.402823466e38f;
  for(int j=jb;j<je;j++){
    us8 v = *(const us8*)(in + (size_t)adj[j]*256 + c);
    float f[8]; us8_to_f(v,f);
    #pragma unroll
    for(int q=0;q<8;q++) m[q]=fminf(m[q],f[q]);
  }
  if(jb==je){
    #pragma unroll
    for(int q=0;q<8;q++) m[q]=0.f;
  }
  *(us8*)(out + (size_t)s*256 + c) = f_to_us8(m);
}

// -------- MFMA GEMM: C[R,CN] = epi(A[R,256or512]_bf16 * Wb[CN,K]^T_bf16) --------
// DIRECT-LOAD structure (no LDS staging, no barriers in the K-loop):
// this is a THIN memory-bound GEMM (K=256/512). Each lane loads its MFMA
// fragments straight from global: af[i] = A[row][kt+q*8.. +7] (16B aligned;
// one wave-instruction touches 16 rows x 64B = full sectors), bfv[j] from the
// L2-resident weight matrix. No barriers -> waves run free, compiler hoists
// next-step loads over MFMAs, TLP supplies outstanding-bytes for HBM latency.
// A is re-read by the 4 col-group waves of the block -> L2-local hits.
// OOB rows clamp to R-1 (their acc rows are never stored; safe for in-place
// because row R-1 belongs to the last block and reads precede the epilogue
// __syncthreads). One block = 128 rows x CN=JT*64 cols, 8 waves (2x4),
// wave tile 64x64 (JT=4). LDS = epilogue buffer only (~34KB).
// __launch_bounds__(512,3): VGPR cap ~170 (acc 64 + frags 32 + pipeline
// headroom, no spill). (512,6) spilled acc in round 1 -- keep the cap loose.
// FLAGS: 1=bias, 2=lrelu, 4=fp32 out (scalar epilogue), 8=splitA (k>=256 from A1)
template<int FLAGS, int JT>
__global__ __launch_bounds__(512, 3)
void gemm_mfma(const u16* A0, const u16* __restrict__ A1,
               const u16* __restrict__ Wb, const float* __restrict__ bias,
               u16* Cb, float* __restrict__ Cf, int R, int K){
  const int CN = JT*64;
  __shared__ u16 sm[64*(JT*64+8)];       // epilogue staging only
  const int t = threadIdx.x;
  const int row0 = blockIdx.x*128;
  const int lane = t&63;
  const int w = t>>6;
  const int wrow = (w>>2)*64, wcol = (w&3)*(JT*16);
  const int lm = lane&15, q = lane>>4;
  f32x4 acc[4][4];
  #pragma unroll
  for(int i=0;i<4;i++)
    #pragma unroll
    for(int j=0;j<JT;j++) acc[i][j] = (f32x4){0.f,0.f,0.f,0.f};

  // per-lane source rows (A rows clamped; OOB results discarded at store)
  int arow[4];
  #pragma unroll
  for(int i=0;i<4;i++){
    int r = row0 + wrow + i*16 + lm;
    arow[i] = r < R ? r : (R-1);
  }
  const u16* brow[JT];
  #pragma unroll
  for(int j=0;j<JT;j++) brow[j] = Wb + (size_t)(wcol + j*16 + lm)*K + q*8;

  #pragma unroll 2
  for(int kt=0; kt<K; kt+=32){
    const u16* Ab = ((FLAGS&8) && kt>=256) ? A1 : A0;
    const int kc = (kt & 255) + q*8;
    bf16x8 af[4], bfv[4];
    #pragma unroll
    for(int i=0;i<4;i++)  af[i]  = *(const bf16x8*)(Ab + (size_t)arow[i]*256 + kc);
    #pragma unroll
    for(int j=0;j<JT;j++) bfv[j] = *(const bf16x8*)(brow[j] + kt);
    #pragma unroll
    for(int i=0;i<4;i++)
      #pragma unroll
      for(int j=0;j<JT;j++)
        acc[i][j] = __builtin_amdgcn_mfma_f32_16x16x32_bf16(af[i], bfv[j], acc[i][j], 0,0,0);
  }

  float bvals[4];
  #pragma unroll
  for(int j=0;j<JT;j++) bvals[j] = (FLAGS&1) ? bias[wcol+j*16+lm] : 0.f;

  if(FLAGS&4){
    // fp32 scalar epilogue (final GEMM only, small)
    #pragma unroll
    for(int j=0;j<JT;j++){
      int col = wcol + j*16 + lm;
      #pragma unroll
      for(int i=0;i<4;i++){
        int rbase = row0 + wrow + i*16 + q*4;
        #pragma unroll
        for(int rg=0;rg<4;rg++){
          int r = rbase+rg;
          if(r>=R) continue;
          float v = acc[i][j][rg] + bvals[j];
          if(FLAGS&2) v = lrelu_f(v);
          Cf[(size_t)r*CN+col] = v;
        }
      }
    }
  } else {
    // bf16 epilogue: 2 half-tile passes through LDS -> full-row us8 stores.
    // First __syncthreads also orders all waves' A-reads before in-place C-writes.
    const int CEPI = CN+8;
    const int ROWU = CN/8;               // us8 per row
    #pragma unroll
    for(int h=0; h<2; h++){
      if((w>>2)==h){
        #pragma unroll
        for(int j=0;j<JT;j++){
          int cl = wcol + j*16 + lm;
          #pragma unroll
          for(int i=0;i<4;i++){
            #pragma unroll
            for(int rg=0;rg<4;rg++){
              float v = acc[i][j][rg] + bvals[j];
              if(FLAGS&2) v = lrelu_f(v);
              sm[(i*16 + q*4 + rg)*CEPI + cl] = f2bf(v);
            }
          }
        }
      }
      __syncthreads();
      #pragma unroll
      for(int it=0; it<64*ROWU/512; it++){
        int idx = it*512 + t;
        int rl = idx/ROWU, c8 = (idx - rl*ROWU)*8;
        int r = row0 + h*64 + rl;
        if(r<R) *(us8*)(Cb + (size_t)r*CN + c8) = *(const us8*)(&sm[rl*CEPI + c8]);
      }
      __syncthreads();
    }
  }
}

// ---------------- host ----------------
extern "C" void kernel_launch(void* const* d_in, const int* in_sizes, int n_in,
                              void* d_out, int out_size, void* d_ws, size_t ws_size,
                              hipStream_t stream){
  const int H = 256;
  const int N = in_sizes[0]/H;
  const int M = in_sizes[1]/H;
  const int E = in_sizes[38]/2;

  const float* x     = (const float*)d_in[0];
  const float* x_e   = (const float*)d_in[1];
  const float* x_st  = (const float*)d_in[2];
  const float* w_in  = (const float*)d_in[3];  const float* b_in  = (const float*)d_in[4];
  const float* w_e   = (const float*)d_in[5];  const float* b_e   = (const float*)d_in[6];
  const float* w_sem = (const float*)d_in[7];  const float* b_sem = (const float*)d_in[8];
  const float* ln_n_g = (const float*)d_in[9]; const float* ln_n_b = (const float*)d_in[10];
  const float* hg_w  = (const float*)d_in[11]; const float* hg_b  = (const float*)d_in[12];
  const float* gns_w = (const float*)d_in[13]; const float* gns_b = (const float*)d_in[14]; const float* gns_ms = (const float*)d_in[15];
  const float* gnl_w = (const float*)d_in[16]; const float* gnl_b = (const float*)d_in[17]; const float* gnl_ms = (const float*)d_in[18];
  const float* gnd_w = (const float*)d_in[19]; const float* gnd_b = (const float*)d_in[20]; const float* gnd_ms = (const float*)d_in[21];
  const float* skip_w = (const float*)d_in[22]; const float* skip_b = (const float*)d_in[23];
  const float* nf_ln1_g = (const float*)d_in[24]; const float* nf_ln1_b = (const float*)d_in[25];
  const float* nf_w = (const float*)d_in[26]; const float* nf_b = (const float*)d_in[27];
  const float* nf_ln2_g = (const float*)d_in[28]; const float* nf_ln2_b = (const float*)d_in[29];
  const float* ef_ln1_g = (const float*)d_in[30]; const float* ef_ln1_b = (const float*)d_in[31];
  const float* ef_w = (const float*)d_in[32]; const float* ef_b = (const float*)d_in[33];
  const float* ef_ln2_g = (const float*)d_in[34]; const float* ef_ln2_b = (const float*)d_in[35];
  const float* lin_w = (const float*)d_in[36]; const float* lin_b = (const float*)d_in[37];
  const int* edge = (const int*)d_in[38];
  const int* src = edge;
  const int* dst = edge + E;
  float* outp = (float*)d_out;

  // workspace carve: bf16 internal buffers (~205 MB) + scratch (~7 MB)
  const size_t NH=(size_t)N*H, MH=(size_t)M*H;
  u16* XS = (u16*)d_ws;      // N x 256
  u16* XN = XS + NH;         // N x 256
  u16* TN = XN + NH;         // N x 256 temp
  u16* XE = TN + NH;         // M x 256
  u16* TM = XE + MH;         // M x 256 temp
  float* dinv = (float*)(TM + MH);   // [N]
  float* binv = dinv + N;            // [M]
  float* stat = binv + M;            // [512]
  float* gA = stat+512; float* gS = gA+256; float* gB = gS+256;
  int* cnt_src = (int*)(gB+256);
  int* cnt_dst = cnt_src + N;
  int* off_src = cnt_dst + M;      // [N+1]
  int* off_dst = off_src + (N+1);  // [M+1]
  int* adj_ds = off_dst + (M+1);   // [E]
  int* adj_sd = adj_ds + E;        // [E]
  int* partial = adj_sd + E;       // [1024]
  // bf16 weight scratch, 16B-aligned
  u16* wb = (u16*)(((uintptr_t)(partial+1024)+15)&~(uintptr_t)15);
  u16* wb_in  = wb;                 // 65536
  u16* wb_sem = wb_in  + 65536;
  u16* wb_e   = wb_sem + 65536;
  u16* wb_hg  = wb_e   + 65536;     // 6*65536
  u16* wb_sk  = wb_hg  + 6*65536;   // 4*65536
  u16* wb_nf  = wb_sk  + 4*65536;   // 131072
  u16* wb_ef  = wb_nf  + 131072;    // 131072
  u16* wb_lin = wb_ef  + 131072;    // 32768

  // ---- weight conversion fp32 -> bf16 ----
  cvt_k<<<CDIV(65536,1024),256,0,stream>>>(w_in, wb_in, 65536);
  cvt_k<<<CDIV(65536,1024),256,0,stream>>>(w_sem, wb_sem, 65536);
  cvt_k<<<CDIV(65536,1024),256,0,stream>>>(w_e, wb_e, 65536);
  cvt_k<<<CDIV(6*65536,1024),256,0,stream>>>(hg_w, wb_hg, 6*65536);
  cvt_k<<<CDIV(4*65536,1024),256,0,stream>>>(skip_w, wb_sk, 4*65536);
  cvt_k<<<CDIV(131072,1024),256,0,stream>>>(nf_w, wb_nf, 131072);
  cvt_k<<<CDIV(131072,1024),256,0,stream>>>(ef_w, wb_ef, 131072);
  cvt_k<<<CDIV(32768,1024),256,0,stream>>>(lin_w, wb_lin, 32768);

  // ---- CSR build ----
  zero_k<<<CDIV(N+M,256),256,0,stream>>>((unsigned*)cnt_src, N+M);
  count_k<<<CDIV(E,256),256,0,stream>>>(src,dst,E,cnt_src,cnt_dst);
  int nbN = CDIV(N,SCAN_CHUNK), nbM = CDIV(M,SCAN_CHUNK);
  scan_pass1<<<nbN,256,0,stream>>>(cnt_src,N,partial);
  scan_pass2<<<1,256,0,stream>>>(partial,nbN);
  scan_pass3<<<nbN,256,0,stream>>>(cnt_src,N,partial,off_src,E);
  scan_pass1<<<nbM,256,0,stream>>>(cnt_dst,M,partial);
  scan_pass2<<<1,256,0,stream>>>(partial,nbM);
  scan_pass3<<<nbM,256,0,stream>>>(cnt_dst,M,partial,off_dst,E);
  copy_int_k<<<CDIV(N,256),256,0,stream>>>(off_src,cnt_src,N);
  copy_int_k<<<CDIV(M,256),256,0,stream>>>(off_dst,cnt_dst,M);
  fill_adj_k<<<CDIV(E,256),256,0,stream>>>(src,dst,E,cnt_src,cnt_dst,adj_sd,adj_ds);
  invdeg_k<<<CDIV(N,256),256,0,stream>>>(off_src,dinv,N);
  invdeg_k<<<CDIV(M,256),256,0,stream>>>(off_dst,binv,M);

  // F: 1=bias, 2=lrelu, 4=fp32 out, 8=splitA ; JT=4 -> CN=256, JT=2 -> CN=128
  auto gemm = [&](int F, const u16* A0, const u16* A1, const u16* Wt, const float* bias,
                  u16* Cb, float* Cf, int R, int K){
    dim3 g(CDIV(R,128));
    switch(F){
      case 0:  gemm_mfma<0,4> <<<g,512,0,stream>>>(A0,A1,Wt,bias,Cb,Cf,R,K); break;
      case 1:  gemm_mfma<1,4> <<<g,512,0,stream>>>(A0,A1,Wt,bias,Cb,Cf,R,K); break;
      case 3:  gemm_mfma<3,4> <<<g,512,0,stream>>>(A0,A1,Wt,bias,Cb,Cf,R,K); break;
      case 5:  gemm_mfma<5,2> <<<g,512,0,stream>>>(A0,A1,Wt,bias,Cb,Cf,R,K); break;
      case 11: gemm_mfma<11,4><<<g,512,0,stream>>>(A0,A1,Wt,bias,Cb,Cf,R,K); break;
    }
  };
  auto colstats = [&](const u16* xx, const u16* x2, const float* w, const float* b,
                      const float* ms, float eps, int R){
    zero_k<<<2,256,0,stream>>>((unsigned*)stat, 512);
    colstat_k<<<256,256,0,stream>>>(xx, x2, stat, R);
    gn_final_k<<<1,256,0,stream>>>(stat, w, b, ms, eps, 1.0f/(float)R, gA,gS,gB);
  };

  // ---- input projections: lrelu(l2n(X) @ W^T + b) ----
  l2norm_k<<<CDIV(N,4),256,0,stream>>>(x_st, TN, N);
  gemm(3, TN, nullptr, wb_in, b_in, XS, nullptr, N, 256);
  l2norm_k<<<CDIV(N,4),256,0,stream>>>(x, TN, N);
  gemm(3, TN, nullptr, wb_sem, b_sem, XN, nullptr, N, 256);
  l2norm_k<<<CDIV(M,4),256,0,stream>>>(x_e, TM, M);
  gemm(3, TM, nullptr, wb_e, b_e, XE, nullptr, M, 256);

  // ---- layers ----
  // hgconv commuted: segsum(X@W) == segsum(X)@W, so the conv GEMM runs at M rows
  // (half of N) and in-place (TM = TM@W is block-row-local, safe).
  for(int i=0;i<2;i++){
    // xs: LN -> GN stats -> seg0(XS)->TM -> TM=TM@W -> xs = lrelu(seg1(TM)+b) + gn(xs)
    ln_rows_k<<<CDIV(N,4),256,0,stream>>>(XS, ln_n_g+i*H, ln_n_b+i*H, N);
    colstats(XS, nullptr, gns_w+i*H, gns_b+i*H, gns_ms+i*H, 256.0f, N);
    seg_sum_k<0><<<CDIV(M,8),256,0,stream>>>(XS, TM, adj_ds, off_dst, binv, nullptr,nullptr,nullptr,nullptr,nullptr, M);
    gemm(0, TM, nullptr, wb_hg+(size_t)(i*3+0)*65536, nullptr, TM, nullptr, M, 256);
    seg_sum_k<1><<<CDIV(N,8),256,0,stream>>>(TM, XS, adj_sd, off_src, dinv, hg_b+(size_t)(i*3+0)*H, XS, gA,gS,gB, N);

    // xn: GN -> seg0(XN)->TM -> TM=TM@W ; skip: TN = XN@skip_w+b ; xn = lrelu(seg1(TM)+b)+TN
    colstats(XN, nullptr, gnl_w+i*H, gnl_b+i*H, gnl_ms+i*H, 1e-5f, N);
    apply_gn_k<<<1024,256,0,stream>>>(XN, nullptr, gA,gS,gB, NH/4);
    seg_sum_k<0><<<CDIV(M,8),256,0,stream>>>(XN, TM, adj_ds, off_dst, binv, nullptr,nullptr,nullptr,nullptr,nullptr, M);
    gemm(0, TM, nullptr, wb_hg+(size_t)(i*3+1)*65536, nullptr, TM, nullptr, M, 256);
    gemm(1, XN, nullptr, wb_sk+(size_t)(i*2+0)*65536, skip_b+(size_t)(i*2+0)*H, TN, nullptr, N, 256);
    seg_sum_k<2><<<CDIV(N,8),256,0,stream>>>(TM, XN, adj_sd, off_src, dinv, hg_b+(size_t)(i*3+1)*H, TN, nullptr,nullptr,nullptr, N);

    // xe: agg=min(xn over dst) -> GN(xe+agg) -> dual conv (GEMM at M) + skip
    seg_min_k<<<CDIV(M,8),256,0,stream>>>(XN, TM, adj_ds, off_dst, M);
    colstats(XE, TM, gnd_w+i*H, gnd_b+i*H, gnd_ms+i*H, 1e-5f, M);
    apply_gn_k<<<1024,256,0,stream>>>(XE, TM, gA,gS,gB, MH/4);
    gemm(0, XE, nullptr, wb_hg+(size_t)(i*3+2)*65536, nullptr, TM, nullptr, M, 256);
    seg_sum_k<0><<<CDIV(N,8),256,0,stream>>>(TM, TN, adj_sd, off_src, dinv, nullptr,nullptr,nullptr,nullptr,nullptr, N);
    gemm(1, XE, nullptr, wb_sk+(size_t)(i*2+1)*65536, skip_b+(size_t)(i*2+1)*H, TM, nullptr, M, 256);
    seg_sum_k<2><<<CDIV(M,8),256,0,stream>>>(TN, XE, adj_ds, off_dst, binv, hg_b+(size_t)(i*3+2)*H, TM, nullptr,nullptr,nullptr, M);
  }

  // ---- head ----
  ln512_k<<<CDIV(N,4),256,0,stream>>>(XS, XN, nf_ln1_g, nf_ln1_b, N);
  gemm(11, XS, XN, wb_nf, nf_b, TN, nullptr, N, 512);   // TN = lrelu(LN(concat) @ nf_w^T + b)
  ln_rows_k<<<CDIV(N,4),256,0,stream>>>(TN, nf_ln2_g, nf_ln2_b, N);
  seg_min_k<<<CDIV(M,8),256,0,stream>>>(TN, TM, adj_ds, off_dst, M);   // xa
  ln512_k<<<CDIV(M,4),256,0,stream>>>(TM, XE, ef_ln1_g, ef_ln1_b, M);
  gemm(11, TM, XE, wb_ef, ef_b, XS, nullptr, M, 512);   // XS[0:M] = lrelu(...)
  ln_rows_k<<<CDIV(M,4),256,0,stream>>>(XS, ef_ln2_g, ef_ln2_b, M);
  gemm(5, XS, nullptr, wb_lin, lin_b, nullptr, outp, M, 256);  // final fp32 out, CN=128
}

// Round 4
// 2020.224 us; speedup vs baseline: 1.0707x; 1.0707x over previous
//
#include <hip/hip_runtime.h>

typedef unsigned short u16;
struct __align__(16) us8 { ushort4 a, b; };
typedef __attribute__((ext_vector_type(8))) short bf16x8;
typedef __attribute__((ext_vector_type(4))) float f32x4;

#define CDIV(a,b) (((a)+(b)-1)/(b))

__device__ __forceinline__ float bf2f(u16 u){ return __uint_as_float(((unsigned)u)<<16); }
__device__ __forceinline__ u16 f2bf(float f){
  unsigned u=__float_as_uint(f);
  unsigned r=u+0x7fffu+((u>>16)&1u);
  return (u16)(r>>16);
}
__device__ __forceinline__ float lrelu_f(float v){ return v>0.f? v:0.01f*v; }
__device__ __forceinline__ float wsum(float v){
  #pragma unroll
  for(int o=32;o>0;o>>=1) v+=__shfl_xor(v,o,64);
  return v;
}
__device__ __forceinline__ void us8_to_f(const us8& v, float* f){
  f[0]=bf2f(v.a.x); f[1]=bf2f(v.a.y); f[2]=bf2f(v.a.z); f[3]=bf2f(v.a.w);
  f[4]=bf2f(v.b.x); f[5]=bf2f(v.b.y); f[6]=bf2f(v.b.z); f[7]=bf2f(v.b.w);
}
__device__ __forceinline__ us8 f_to_us8(const float* f){
  us8 v;
  v.a.x=f2bf(f[0]); v.a.y=f2bf(f[1]); v.a.z=f2bf(f[2]); v.a.w=f2bf(f[3]);
  v.b.x=f2bf(f[4]); v.b.y=f2bf(f[5]); v.b.z=f2bf(f[6]); v.b.w=f2bf(f[7]);
  return v;
}

// ---------------- utility ----------------
__global__ void zero_k(unsigned* __restrict__ p, int n){
  int i=blockIdx.x*256+threadIdx.x; if(i<n) p[i]=0u;
}
__global__ void cvt_k(const float* __restrict__ in, u16* __restrict__ out, int n){
  int i = (blockIdx.x*256+threadIdx.x)*4;
  if(i+3<n){
    float4 v=*(const float4*)(in+i);
    ushort4 o; o.x=f2bf(v.x); o.y=f2bf(v.y); o.z=f2bf(v.z); o.w=f2bf(v.w);
    *(ushort4*)(out+i)=o;
  } else {
    for(int q=0;q<4&&i+q<n;q++) out[i+q]=f2bf(in[i+q]);
  }
}

// ---------------- CSR build ----------------
__global__ void count_k(const int* __restrict__ src, const int* __restrict__ dst, int E,
                        int* __restrict__ cnt_src, int* __restrict__ cnt_dst){
  int e = blockIdx.x*256+threadIdx.x;
  if(e>=E) return;
  atomicAdd(&cnt_src[src[e]],1);
  atomicAdd(&cnt_dst[dst[e]],1);
}

#define SCAN_CHUNK 1024
__global__ void scan_pass1(const int* __restrict__ in, int n, int* __restrict__ partial){
  __shared__ int red[256];
  int base = blockIdx.x*SCAN_CHUNK;
  int s=0;
  for(int j=threadIdx.x;j<SCAN_CHUNK;j+=256){ int i=base+j; if(i<n) s+=in[i]; }
  red[threadIdx.x]=s; __syncthreads();
  for(int st=128;st>0;st>>=1){ if(threadIdx.x<st) red[threadIdx.x]+=red[threadIdx.x+st]; __syncthreads(); }
  if(threadIdx.x==0) partial[blockIdx.x]=red[0];
}
__global__ void scan_pass2(int* __restrict__ partial, int nb){
  __shared__ int buf[1024];
  for(int j=threadIdx.x;j<1024;j+=256) buf[j] = (j<nb)? partial[j]:0;
  __syncthreads();
  if(threadIdx.x==0){ int run=0; for(int j=0;j<nb;j++){ int v=buf[j]; buf[j]=run; run+=v; } }
  __syncthreads();
  for(int j=threadIdx.x;j<nb;j+=256) partial[j]=buf[j];
}
__global__ void scan_pass3(const int* __restrict__ in, int n, const int* __restrict__ partial,
                           int* __restrict__ out, int total){
  __shared__ int red[256];
  int base = blockIdx.x*SCAN_CHUNK;
  int j0 = base + threadIdx.x*4;
  int v[4]; int s=0;
  #pragma unroll
  for(int q=0;q<4;q++){ int i=j0+q; v[q]=(i<n)? in[i]:0; s+=v[q]; }
  red[threadIdx.x]=s; __syncthreads();
  if(threadIdx.x==0){ int run=0; for(int j=0;j<256;j++){ int t=red[j]; red[j]=run; run+=t; } }
  __syncthreads();
  int run = partial[blockIdx.x] + red[threadIdx.x];
  #pragma unroll
  for(int q=0;q<4;q++){ int i=j0+q; if(i<n) out[i]=run; run+=v[q]; }
  if(base==0 && threadIdx.x==0) out[n]=total;
}
__global__ void copy_int_k(const int* __restrict__ in, int* __restrict__ out, int n){
  int i=blockIdx.x*256+threadIdx.x;
  if(i<n) out[i]=in[i];
}
__global__ void fill_adj_k(const int* __restrict__ src, const int* __restrict__ dst, int E,
                           int* __restrict__ cur_src, int* __restrict__ cur_dst,
                           int* __restrict__ adj_sd, int* __restrict__ adj_ds){
  int e = blockIdx.x*256+threadIdx.x;
  if(e>=E) return;
  int s=src[e], d=dst[e];
  int p = atomicAdd(&cur_dst[d],1); adj_ds[p]=s;   // dst-grouped, values = src
  int q = atomicAdd(&cur_src[s],1); adj_sd[q]=d;   // src-grouped, values = dst
}
__global__ void invdeg_k(const int* __restrict__ off, float* __restrict__ inv, int S){
  int s=blockIdx.x*256+threadIdx.x;
  if(s>=S) return;
  int d=off[s+1]-off[s];
  inv[s] = d>0 ? 1.0f/(float)d : 0.0f;
}

// ---------------- row-wise ops (wave per row, H=256) ----------------
__global__ void l2norm_k(const float* __restrict__ in, u16* __restrict__ out, int R){
  int r = blockIdx.x*4 + (threadIdx.x>>6);
  if(r>=R) return;
  int c = (threadIdx.x&63)*4;
  float4 v = *(const float4*)(in + (size_t)r*256 + c);
  float q = wsum(v.x*v.x+v.y*v.y+v.z*v.z+v.w*v.w);
  float sc = 1.0f/fmaxf(sqrtf(q),1e-12f);
  ushort4 o; o.x=f2bf(v.x*sc); o.y=f2bf(v.y*sc); o.z=f2bf(v.z*sc); o.w=f2bf(v.w*sc);
  *(ushort4*)(out + (size_t)r*256 + c) = o;
}

__global__ void ln_rows_k(u16* __restrict__ x, const float* __restrict__ g,
                          const float* __restrict__ b, int R){
  int r = blockIdx.x*4 + (threadIdx.x>>6);
  if(r>=R) return;
  int lane = threadIdx.x&63; int c = lane*4;
  u16* row = x + (size_t)r*256;
  ushort4 u = *(const ushort4*)(row + c);
  float v0=bf2f(u.x), v1=bf2f(u.y), v2=bf2f(u.z), v3=bf2f(u.w);
  float mean = wsum(v0+v1+v2+v3) * (1.f/256.f);
  float d0=v0-mean,d1=v1-mean,d2=v2-mean,d3=v3-mean;
  float var = wsum(d0*d0+d1*d1+d2*d2+d3*d3) * (1.f/256.f);
  float inv = 1.0f/sqrtf(var + 1e-5f);
  ushort4 ov;
  ov.x=f2bf(d0*inv*g[c+0]+b[c+0]);
  ov.y=f2bf(d1*inv*g[c+1]+b[c+1]);
  ov.z=f2bf(d2*inv*g[c+2]+b[c+2]);
  ov.w=f2bf(d3*inv*g[c+3]+b[c+3]);
  *(ushort4*)(row + c) = ov;
}

// joint LayerNorm over virtual concat [L|R], width 512, in place
__global__ void ln512_k(u16* __restrict__ Lb, u16* __restrict__ Rb,
                        const float* __restrict__ g, const float* __restrict__ b, int R){
  int r = blockIdx.x*4 + (threadIdx.x>>6);
  if(r>=R) return;
  int lane = threadIdx.x&63; int c = lane*4;
  u16* rowL = Lb + (size_t)r*256;
  u16* rowR = Rb + (size_t)r*256;
  ushort4 ul = *(const ushort4*)(rowL + c);
  ushort4 ur = *(const ushort4*)(rowR + c);
  float l0=bf2f(ul.x), l1=bf2f(ul.y), l2=bf2f(ul.z), l3=bf2f(ul.w);
  float r0=bf2f(ur.x), r1=bf2f(ur.y), r2=bf2f(ur.z), r3=bf2f(ur.w);
  float mean = wsum(l0+l1+l2+l3+r0+r1+r2+r3) * (1.f/512.f);
  float a0=l0-mean,a1=l1-mean,a2=l2-mean,a3=l3-mean;
  float b0=r0-mean,b1=r1-mean,b2=r2-mean,b3=r3-mean;
  float var = wsum(a0*a0+a1*a1+a2*a2+a3*a3+b0*b0+b1*b1+b2*b2+b3*b3) * (1.f/512.f);
  float inv = 1.0f/sqrtf(var + 1e-5f);
  int cr = 256+c;
  ushort4 ovl, ovr;
  ovl.x=f2bf(a0*inv*g[c+0]+b[c+0]);
  ovl.y=f2bf(a1*inv*g[c+1]+b[c+1]);
  ovl.z=f2bf(a2*inv*g[c+2]+b[c+2]);
  ovl.w=f2bf(a3*inv*g[c+3]+b[c+3]);
  ovr.x=f2bf(b0*inv*g[cr+0]+b[cr+0]);
  ovr.y=f2bf(b1*inv*g[cr+1]+b[cr+1]);
  ovr.z=f2bf(b2*inv*g[cr+2]+b[cr+2]);
  ovr.w=f2bf(b3*inv*g[cr+3]+b[cr+3]);
  *(ushort4*)(rowL + c) = ovl;
  *(ushort4*)(rowR + c) = ovr;
}

// ---------------- GraphNorm ----------------
__global__ void colstat_k(const u16* __restrict__ x, const u16* __restrict__ x2,
                          float* __restrict__ stat, int R){
  __shared__ float sh[512];
  int tid = threadIdx.x;
  for(int j=tid;j<512;j+=256) sh[j]=0.f;
  __syncthreads();
  int c = (tid&63)*4;
  float s0=0,s1=0,s2=0,s3=0,q0=0,q1=0,q2=0,q3=0;
  for(int r=blockIdx.x*4+(tid>>6); r<R; r+=gridDim.x*4){
    ushort4 u = *(const ushort4*)(x + (size_t)r*256 + c);
    float v0=bf2f(u.x), v1=bf2f(u.y), v2=bf2f(u.z), v3=bf2f(u.w);
    if(x2){
      ushort4 w = *(const ushort4*)(x2 + (size_t)r*256 + c);
      v0+=bf2f(w.x); v1+=bf2f(w.y); v2+=bf2f(w.z); v3+=bf2f(w.w);
    }
    s0+=v0; s1+=v1; s2+=v2; s3+=v3;
    q0+=v0*v0; q1+=v1*v1; q2+=v2*v2; q3+=v3*v3;
  }
  atomicAdd(&sh[c+0],s0); atomicAdd(&sh[c+1],s1);
  atomicAdd(&sh[c+2],s2); atomicAdd(&sh[c+3],s3);
  atomicAdd(&sh[256+c+0],q0); atomicAdd(&sh[256+c+1],q1);
  atomicAdd(&sh[256+c+2],q2); atomicAdd(&sh[256+c+3],q3);
  __syncthreads();
  for(int j=tid;j<512;j+=256) atomicAdd(&stat[j], sh[j]);
}
__global__ void gn_final_k(const float* __restrict__ stat, const float* __restrict__ w,
                           const float* __restrict__ b, const float* __restrict__ ms,
                           float eps, float invR,
                           float* __restrict__ gA, float* __restrict__ gS, float* __restrict__ gB){
  int c=threadIdx.x;
  float mean = stat[c]*invR;
  float a = mean*ms[c];
  float ex2 = stat[256+c]*invR;
  float var = ex2 - 2.f*a*mean + a*a;     // E[(x-a)^2]
  gA[c]=a;
  gS[c]=w[c]/sqrtf(var+eps);
  gB[c]=b[c];
}
__global__ void apply_gn_k(u16* __restrict__ x, const u16* __restrict__ add,
                           const float* __restrict__ gA, const float* __restrict__ gS,
                           const float* __restrict__ gB, size_t n4){
  size_t stride = (size_t)gridDim.x*256;
  for(size_t p=(size_t)blockIdx.x*256+threadIdx.x; p<n4; p+=stride){
    int c = (int)(p&63)*4;
    ushort4 u = ((const ushort4*)x)[p];
    float v0=bf2f(u.x), v1=bf2f(u.y), v2=bf2f(u.z), v3=bf2f(u.w);
    if(add){
      ushort4 a = ((const ushort4*)add)[p];
      v0+=bf2f(a.x); v1+=bf2f(a.y); v2+=bf2f(a.z); v3+=bf2f(a.w);
    }
    v0 = fmaf(gS[c+0], v0-gA[c+0], gB[c+0]);
    v1 = fmaf(gS[c+1], v1-gA[c+1], gB[c+1]);
    v2 = fmaf(gS[c+2], v2-gA[c+2], gB[c+2]);
    v3 = fmaf(gS[c+3], v3-gA[c+3], gB[c+3]);
    ushort4 o; o.x=f2bf(v0); o.y=f2bf(v1); o.z=f2bf(v2); o.w=f2bf(v3);
    ((ushort4*)x)[p]=o;
  }
}

// ---------------- segment gathers (half-wave per segment, 8 cols/lane) ----------------
// MODE 0: out[s] = inv[s]*sum
// MODE 1: out[s] = lrelu(inv[s]*sum + bias) + gS*(resid[s]-gA)+gB
// MODE 2: out[s] = lrelu(inv[s]*sum + bias) + resid[s]
template<int MODE>
__global__ void seg_sum_k(const u16* __restrict__ in, u16* __restrict__ out,
    const int* __restrict__ adj, const int* __restrict__ off,
    const float* __restrict__ inv, const float* __restrict__ bias,
    const u16* __restrict__ resid,
    const float* __restrict__ gA, const float* __restrict__ gS, const float* __restrict__ gB,
    int S){
  int s = blockIdx.x*8 + (threadIdx.x>>5);
  if(s>=S) return;
  int c = (threadIdx.x&31)*8;
  int jb=off[s], je=off[s+1];
  float a[8]={0.f,0.f,0.f,0.f,0.f,0.f,0.f,0.f};
  for(int j=jb;j<je;j++){
    us8 v = *(const us8*)(in + (size_t)adj[j]*256 + c);
    float f[8]; us8_to_f(v,f);
    #pragma unroll
    for(int q=0;q<8;q++) a[q]+=f[q];
  }
  float sc = inv[s];
  float o[8];
  if(MODE==0){
    #pragma unroll
    for(int q=0;q<8;q++) o[q]=a[q]*sc;
  } else {
    #pragma unroll
    for(int q=0;q<8;q++) o[q] = lrelu_f(fmaf(a[q],sc,bias[c+q]));
    us8 p = *(const us8*)(resid + (size_t)s*256 + c);
    float pf[8]; us8_to_f(p,pf);
    if(MODE==1){
      #pragma unroll
      for(int q=0;q<8;q++) o[q] += fmaf(gS[c+q], pf[q]-gA[c+q], gB[c+q]);
    } else {
      #pragma unroll
      for(int q=0;q<8;q++) o[q] += pf[q];
    }
  }
  *(us8*)(out + (size_t)s*256 + c) = f_to_us8(o);
}

__global__ void seg_min_k(const u16* __restrict__ in, u16* __restrict__ out,
    const int* __restrict__ adj, const int* __restrict__ off, int S){
  int s = blockIdx.x*8 + (threadIdx.x>>5);
  if(s>=S) return;
  int c = (threadIdx.x&31)*8;
  int jb=off[s], je=off[s+1];
  float m[8];
  #pragma unroll
  for(int q=0;q<8;q++) m[q]=3.402823466e38f;
  for(int j=jb;j<je;j++){
    us8 v = *(const us8*)(in + (size_t)adj[j]*256 + c);
    float f[8]; us8_to_f(v,f);
    #pragma unroll
    for(int q=0;q<8;q++) m[q]=fminf(m[q],f[q]);
  }
  if(jb==je){
    #pragma unroll
    for(int q=0;q<8;q++) m[q]=0.f;
  }
  *(us8*)(out + (size_t)s*256 + c) = f_to_us8(m);
}

// -------- MFMA GEMM: C[R,CN] = epi(A[R,256or512]_bf16 * Wb[CN,K]^T_bf16) --------
// ROW-CONTIGUOUS LDS staging (round-4 structure):
// Round-3 evidence: direct fragment loads walk A in 64B column slabs at 512B
// row stride -> HBM efficiency ~13% (824 GB/s measured, ideal traffic). Fix:
// stage the whole 128x256 A-tile (64KB) into LDS with a LINEAR contiguous
// copy -- thread t, pass p reads 16B at linear idx p*512+t, so each wave-
// instruction covers 1KB contiguous and each pass 8KB contiguous. 4 loads in
// flight before the 4 ds_writes (Little's law: 4KB/wave x 16 waves/CU >> 9KB
// needed for peak BW). K-loop reads fragments from LDS; B direct from global
// (W is 128KB, L2-resident). One __syncthreads after staging, one after the
// K-loop (epilogue reuses the As LDS region).
// LDS chunk swizzle: phys_chunk = chunk ^ (row&7) on BOTH write and read side
// (within 128B granules) -> conflict-free b128 reads (else lanes lm=0..15 at
// 512B row stride all hit one bank quad = 16-way).
// In-place (Cb==A0) safe: A fully staged before any C write; blocks read only
// their own 128 rows. OOB rows clamp to R-1 (results discarded at store).
// __launch_bounds__(512,3): VGPR cap ~168. (512,6) spilled acc in round 1.
// FLAGS: 1=bias, 2=lrelu, 4=fp32 out (scalar epilogue), 8=splitA (k>=256 from A1)
template<int FLAGS, int JT>
__global__ __launch_bounds__(512, 3)
void gemm_mfma(const u16* A0, const u16* __restrict__ A1,
               const u16* __restrict__ Wb, const float* __restrict__ bias,
               u16* Cb, float* __restrict__ Cf, int R, int K){
  const int CN = JT*64;
  __shared__ u16 sm[128*256];            // As tile (64KB); epilogue reuses as [64][CN+8]
  u16* As = sm;
  const int t = threadIdx.x;
  const int row0 = blockIdx.x*128;
  const int lane = t&63;
  const int w = t>>6;
  const int wrow = (w>>2)*64, wcol = (w&3)*(JT*16);
  const int lm = lane&15, q = lane>>4;
  f32x4 acc[4][4];
  #pragma unroll
  for(int i=0;i<4;i++)
    #pragma unroll
    for(int j=0;j<JT;j++) acc[i][j] = (f32x4){0.f,0.f,0.f,0.f};

  const u16* brow[JT];
  #pragma unroll
  for(int j=0;j<JT;j++) brow[j] = Wb + (size_t)(wcol + j*16 + lm)*K + q*8;

  // stage 128x256 A-tile: linear contiguous global reads, swizzled LDS writes
  auto stage = [&](const u16* Ab){
    #pragma unroll
    for(int h=0; h<2; h++){
      us8 sv[4];
      #pragma unroll
      for(int p=0;p<4;p++){
        int idx = (h*4+p)*512 + t;       // 16B units, linear over the tile
        int row = idx>>5, ch = idx&31;
        int rg = row0+row; rg = rg<R ? rg : (R-1);
        sv[p] = *(const us8*)(Ab + (size_t)rg*256 + ch*8);
      }
      #pragma unroll
      for(int p=0;p<4;p++){
        int idx = (h*4+p)*512 + t;
        int row = idx>>5, ch = idx&31;
        *(us8*)(&As[row*256 + ((ch^(row&7))<<3)]) = sv[p];
      }
    }
    __syncthreads();
  };

  const int nph = (FLAGS&8) ? 2 : 1;
  for(int ph=0; ph<nph; ph++){
    stage(ph ? A1 : A0);
    const int kb = ph<<8;                // B column offset for this phase
    #pragma unroll 2
    for(int st=0; st<8; st++){
      bf16x8 af[4], bfv[4];
      #pragma unroll
      for(int j=0;j<JT;j++) bfv[j] = *(const bf16x8*)(brow[j] + kb + st*32);
      #pragma unroll
      for(int i=0;i<4;i++)
        af[i] = *(const bf16x8*)(&As[(wrow + i*16 + lm)*256 + ((((st<<2)+q)^(lm&7))<<3)]);
      #pragma unroll
      for(int i=0;i<4;i++)
        #pragma unroll
        for(int j=0;j<JT;j++)
          acc[i][j] = __builtin_amdgcn_mfma_f32_16x16x32_bf16(af[i], bfv[j], acc[i][j], 0,0,0);
    }
    __syncthreads();                     // As reusable (next phase stage / epilogue)
  }

  float bvals[4];
  #pragma unroll
  for(int j=0;j<JT;j++) bvals[j] = (FLAGS&1) ? bias[wcol+j*16+lm] : 0.f;

  if(FLAGS&4){
    // fp32 scalar epilogue (final GEMM only, small)
    #pragma unroll
    for(int j=0;j<JT;j++){
      int col = wcol + j*16 + lm;
      #pragma unroll
      for(int i=0;i<4;i++){
        int rbase = row0 + wrow + i*16 + q*4;
        #pragma unroll
        for(int rg=0;rg<4;rg++){
          int r = rbase+rg;
          if(r>=R) continue;
          float v = acc[i][j][rg] + bvals[j];
          if(FLAGS&2) v = lrelu_f(v);
          Cf[(size_t)r*CN+col] = v;
        }
      }
    }
  } else {
    // bf16 epilogue: 2 half-tile passes through LDS -> full-row us8 stores
    const int CEPI = CN+8;
    const int ROWU = CN/8;               // us8 per row
    #pragma unroll
    for(int h=0; h<2; h++){
      if((w>>2)==h){
        #pragma unroll
        for(int j=0;j<JT;j++){
          int cl = wcol + j*16 + lm;
          #pragma unroll
          for(int i=0;i<4;i++){
            #pragma unroll
            for(int rg=0;rg<4;rg++){
              float v = acc[i][j][rg] + bvals[j];
              if(FLAGS&2) v = lrelu_f(v);
              sm[(i*16 + q*4 + rg)*CEPI + cl] = f2bf(v);
            }
          }
        }
      }
      __syncthreads();
      #pragma unroll
      for(int it=0; it<64*ROWU/512; it++){
        int idx = it*512 + t;
        int rl = idx/ROWU, c8 = (idx - rl*ROWU)*8;
        int r = row0 + h*64 + rl;
        if(r<R) *(us8*)(Cb + (size_t)r*CN + c8) = *(const us8*)(&sm[rl*CEPI + c8]);
      }
      __syncthreads();
    }
  }
}

// ---------------- host ----------------
extern "C" void kernel_launch(void* const* d_in, const int* in_sizes, int n_in,
                              void* d_out, int out_size, void* d_ws, size_t ws_size,
                              hipStream_t stream){
  const int H = 256;
  const int N = in_sizes[0]/H;
  const int M = in_sizes[1]/H;
  const int E = in_sizes[38]/2;

  const float* x     = (const float*)d_in[0];
  const float* x_e   = (const float*)d_in[1];
  const float* x_st  = (const float*)d_in[2];
  const float* w_in  = (const float*)d_in[3];  const float* b_in  = (const float*)d_in[4];
  const float* w_e   = (const float*)d_in[5];  const float* b_e   = (const float*)d_in[6];
  const float* w_sem = (const float*)d_in[7];  const float* b_sem = (const float*)d_in[8];
  const float* ln_n_g = (const float*)d_in[9]; const float* ln_n_b = (const float*)d_in[10];
  const float* hg_w  = (const float*)d_in[11]; const float* hg_b  = (const float*)d_in[12];
  const float* gns_w = (const float*)d_in[13]; const float* gns_b = (const float*)d_in[14]; const float* gns_ms = (const float*)d_in[15];
  const float* gnl_w = (const float*)d_in[16]; const float* gnl_b = (const float*)d_in[17]; const float* gnl_ms = (const float*)d_in[18];
  const float* gnd_w = (const float*)d_in[19]; const float* gnd_b = (const float*)d_in[20]; const float* gnd_ms = (const float*)d_in[21];
  const float* skip_w = (const float*)d_in[22]; const float* skip_b = (const float*)d_in[23];
  const float* nf_ln1_g = (const float*)d_in[24]; const float* nf_ln1_b = (const float*)d_in[25];
  const float* nf_w = (const float*)d_in[26]; const float* nf_b = (const float*)d_in[27];
  const float* nf_ln2_g = (const float*)d_in[28]; const float* nf_ln2_b = (const float*)d_in[29];
  const float* ef_ln1_g = (const float*)d_in[30]; const float* ef_ln1_b = (const float*)d_in[31];
  const float* ef_w = (const float*)d_in[32]; const float* ef_b = (const float*)d_in[33];
  const float* ef_ln2_g = (const float*)d_in[34]; const float* ef_ln2_b = (const float*)d_in[35];
  const float* lin_w = (const float*)d_in[36]; const float* lin_b = (const float*)d_in[37];
  const int* edge = (const int*)d_in[38];
  const int* src = edge;
  const int* dst = edge + E;
  float* outp = (float*)d_out;

  // workspace carve: bf16 internal buffers (~205 MB) + scratch (~7 MB)
  const size_t NH=(size_t)N*H, MH=(size_t)M*H;
  u16* XS = (u16*)d_ws;      // N x 256
  u16* XN = XS + NH;         // N x 256
  u16* TN = XN + NH;         // N x 256 temp
  u16* XE = TN + NH;         // M x 256
  u16* TM = XE + MH;         // M x 256 temp
  float* dinv = (float*)(TM + MH);   // [N]
  float* binv = dinv + N;            // [M]
  float* stat = binv + M;            // [512]
  float* gA = stat+512; float* gS = gA+256; float* gB = gS+256;
  int* cnt_src = (int*)(gB+256);
  int* cnt_dst = cnt_src + N;
  int* off_src = cnt_dst + M;      // [N+1]
  int* off_dst = off_src + (N+1);  // [M+1]
  int* adj_ds = off_dst + (M+1);   // [E]
  int* adj_sd = adj_ds + E;        // [E]
  int* partial = adj_sd + E;       // [1024]
  // bf16 weight scratch, 16B-aligned
  u16* wb = (u16*)(((uintptr_t)(partial+1024)+15)&~(uintptr_t)15);
  u16* wb_in  = wb;                 // 65536
  u16* wb_sem = wb_in  + 65536;
  u16* wb_e   = wb_sem + 65536;
  u16* wb_hg  = wb_e   + 65536;     // 6*65536
  u16* wb_sk  = wb_hg  + 6*65536;   // 4*65536
  u16* wb_nf  = wb_sk  + 4*65536;   // 131072
  u16* wb_ef  = wb_nf  + 131072;    // 131072
  u16* wb_lin = wb_ef  + 131072;    // 32768

  // ---- weight conversion fp32 -> bf16 ----
  cvt_k<<<CDIV(65536,1024),256,0,stream>>>(w_in, wb_in, 65536);
  cvt_k<<<CDIV(65536,1024),256,0,stream>>>(w_sem, wb_sem, 65536);
  cvt_k<<<CDIV(65536,1024),256,0,stream>>>(w_e, wb_e, 65536);
  cvt_k<<<CDIV(6*65536,1024),256,0,stream>>>(hg_w, wb_hg, 6*65536);
  cvt_k<<<CDIV(4*65536,1024),256,0,stream>>>(skip_w, wb_sk, 4*65536);
  cvt_k<<<CDIV(131072,1024),256,0,stream>>>(nf_w, wb_nf, 131072);
  cvt_k<<<CDIV(131072,1024),256,0,stream>>>(ef_w, wb_ef, 131072);
  cvt_k<<<CDIV(32768,1024),256,0,stream>>>(lin_w, wb_lin, 32768);

  // ---- CSR build ----
  zero_k<<<CDIV(N+M,256),256,0,stream>>>((unsigned*)cnt_src, N+M);
  count_k<<<CDIV(E,256),256,0,stream>>>(src,dst,E,cnt_src,cnt_dst);
  int nbN = CDIV(N,SCAN_CHUNK), nbM = CDIV(M,SCAN_CHUNK);
  scan_pass1<<<nbN,256,0,stream>>>(cnt_src,N,partial);
  scan_pass2<<<1,256,0,stream>>>(partial,nbN);
  scan_pass3<<<nbN,256,0,stream>>>(cnt_src,N,partial,off_src,E);
  scan_pass1<<<nbM,256,0,stream>>>(cnt_dst,M,partial);
  scan_pass2<<<1,256,0,stream>>>(partial,nbM);
  scan_pass3<<<nbM,256,0,stream>>>(cnt_dst,M,partial,off_dst,E);
  copy_int_k<<<CDIV(N,256),256,0,stream>>>(off_src,cnt_src,N);
  copy_int_k<<<CDIV(M,256),256,0,stream>>>(off_dst,cnt_dst,M);
  fill_adj_k<<<CDIV(E,256),256,0,stream>>>(src,dst,E,cnt_src,cnt_dst,adj_sd,adj_ds);
  invdeg_k<<<CDIV(N,256),256,0,stream>>>(off_src,dinv,N);
  invdeg_k<<<CDIV(M,256),256,0,stream>>>(off_dst,binv,M);

  // F: 1=bias, 2=lrelu, 4=fp32 out, 8=splitA ; JT=4 -> CN=256, JT=2 -> CN=128
  auto gemm = [&](int F, const u16* A0, const u16* A1, const u16* Wt, const float* bias,
                  u16* Cb, float* Cf, int R, int K){
    dim3 g(CDIV(R,128));
    switch(F){
      case 0:  gemm_mfma<0,4> <<<g,512,0,stream>>>(A0,A1,Wt,bias,Cb,Cf,R,K); break;
      case 1:  gemm_mfma<1,4> <<<g,512,0,stream>>>(A0,A1,Wt,bias,Cb,Cf,R,K); break;
      case 3:  gemm_mfma<3,4> <<<g,512,0,stream>>>(A0,A1,Wt,bias,Cb,Cf,R,K); break;
      case 5:  gemm_mfma<5,2> <<<g,512,0,stream>>>(A0,A1,Wt,bias,Cb,Cf,R,K); break;
      case 11: gemm_mfma<11,4><<<g,512,0,stream>>>(A0,A1,Wt,bias,Cb,Cf,R,K); break;
    }
  };
  auto colstats = [&](const u16* xx, const u16* x2, const float* w, const float* b,
                      const float* ms, float eps, int R){
    zero_k<<<2,256,0,stream>>>((unsigned*)stat, 512);
    colstat_k<<<256,256,0,stream>>>(xx, x2, stat, R);
    gn_final_k<<<1,256,0,stream>>>(stat, w, b, ms, eps, 1.0f/(float)R, gA,gS,gB);
  };

  // ---- input projections: lrelu(l2n(X) @ W^T + b) ----
  l2norm_k<<<CDIV(N,4),256,0,stream>>>(x_st, TN, N);
  gemm(3, TN, nullptr, wb_in, b_in, XS, nullptr, N, 256);
  l2norm_k<<<CDIV(N,4),256,0,stream>>>(x, TN, N);
  gemm(3, TN, nullptr, wb_sem, b_sem, XN, nullptr, N, 256);
  l2norm_k<<<CDIV(M,4),256,0,stream>>>(x_e, TM, M);
  gemm(3, TM, nullptr, wb_e, b_e, XE, nullptr, M, 256);

  // ---- layers ----
  // hgconv commuted: segsum(X@W) == segsum(X)@W, so the conv GEMM runs at M rows
  // (half of N) and in-place (TM = TM@W is block-row-local, safe).
  for(int i=0;i<2;i++){
    // xs: LN -> GN stats -> seg0(XS)->TM -> TM=TM@W -> xs = lrelu(seg1(TM)+b) + gn(xs)
    ln_rows_k<<<CDIV(N,4),256,0,stream>>>(XS, ln_n_g+i*H, ln_n_b+i*H, N);
    colstats(XS, nullptr, gns_w+i*H, gns_b+i*H, gns_ms+i*H, 256.0f, N);
    seg_sum_k<0><<<CDIV(M,8),256,0,stream>>>(XS, TM, adj_ds, off_dst, binv, nullptr,nullptr,nullptr,nullptr,nullptr, M);
    gemm(0, TM, nullptr, wb_hg+(size_t)(i*3+0)*65536, nullptr, TM, nullptr, M, 256);
    seg_sum_k<1><<<CDIV(N,8),256,0,stream>>>(TM, XS, adj_sd, off_src, dinv, hg_b+(size_t)(i*3+0)*H, XS, gA,gS,gB, N);

    // xn: GN -> seg0(XN)->TM -> TM=TM@W ; skip: TN = XN@skip_w+b ; xn = lrelu(seg1(TM)+b)+TN
    colstats(XN, nullptr, gnl_w+i*H, gnl_b+i*H, gnl_ms+i*H, 1e-5f, N);
    apply_gn_k<<<1024,256,0,stream>>>(XN, nullptr, gA,gS,gB, NH/4);
    seg_sum_k<0><<<CDIV(M,8),256,0,stream>>>(XN, TM, adj_ds, off_dst, binv, nullptr,nullptr,nullptr,nullptr,nullptr, M);
    gemm(0, TM, nullptr, wb_hg+(size_t)(i*3+1)*65536, nullptr, TM, nullptr, M, 256);
    gemm(1, XN, nullptr, wb_sk+(size_t)(i*2+0)*65536, skip_b+(size_t)(i*2+0)*H, TN, nullptr, N, 256);
    seg_sum_k<2><<<CDIV(N,8),256,0,stream>>>(TM, XN, adj_sd, off_src, dinv, hg_b+(size_t)(i*3+1)*H, TN, nullptr,nullptr,nullptr, N);

    // xe: agg=min(xn over dst) -> GN(xe+agg) -> dual conv (GEMM at M) + skip
    seg_min_k<<<CDIV(M,8),256,0,stream>>>(XN, TM, adj_ds, off_dst, M);
    colstats(XE, TM, gnd_w+i*H, gnd_b+i*H, gnd_ms+i*H, 1e-5f, M);
    apply_gn_k<<<1024,256,0,stream>>>(XE, TM, gA,gS,gB, MH/4);
    gemm(0, XE, nullptr, wb_hg+(size_t)(i*3+2)*65536, nullptr, TM, nullptr, M, 256);
    seg_sum_k<0><<<CDIV(N,8),256,0,stream>>>(TM, TN, adj_sd, off_src, dinv, nullptr,nullptr,nullptr,nullptr,nullptr, N);
    gemm(1, XE, nullptr, wb_sk+(size_t)(i*2+1)*65536, skip_b+(size_t)(i*2+1)*H, TM, nullptr, M, 256);
    seg_sum_k<2><<<CDIV(M,8),256,0,stream>>>(TN, XE, adj_ds, off_dst, binv, hg_b+(size_t)(i*3+2)*H, TM, nullptr,nullptr,nullptr, M);
  }

  // ---- head ----
  ln512_k<<<CDIV(N,4),256,0,stream>>>(XS, XN, nf_ln1_g, nf_ln1_b, N);
  gemm(11, XS, XN, wb_nf, nf_b, TN, nullptr, N, 512);   // TN = lrelu(LN(concat) @ nf_w^T + b)
  ln_rows_k<<<CDIV(N,4),256,0,stream>>>(TN, nf_ln2_g, nf_ln2_b, N);
  seg_min_k<<<CDIV(M,8),256,0,stream>>>(TN, TM, adj_ds, off_dst, M);   // xa
  ln512_k<<<CDIV(M,4),256,0,stream>>>(TM, XE, ef_ln1_g, ef_ln1_b, M);
  gemm(11, TM, XE, wb_ef, ef_b, XS, nullptr, M, 512);   // XS[0:M] = lrelu(...)
  ln_rows_k<<<CDIV(M,4),256,0,stream>>>(XS, ef_ln2_g, ef_ln2_b, M);
  gemm(5, XS, nullptr, wb_lin, lin_b, nullptr, outp, M, 256);  // final fp32 out, CN=128
}